// Round 1
// baseline (253.286 us; speedup 1.0000x reference)
//
#include <hip/hip_runtime.h>

// ---- problem constants -----------------------------------------------------
#define IN_DIM   1024
#define OUT_DIM  1024
#define BATCH    4096
#define NC       8        // N_COEFFS
#define NK       12       // N_KNOTS
#define KSPLINE  (IN_DIM * NC)      // 8192
#define KDIM     (KSPLINE + IN_DIM) // 9216
#define EPS      1e-8f

#define NBLK_A   ((IN_DIM / 256) * (BATCH / 16))      // 1024 A-builder blocks
#define NBLK_W   ((OUT_DIM * (KDIM / 4)) / 256)       // 9216 W-builder blocks

// ---- gemm geometry: 256x256 tile, 8 waves, BK=32, 4-slot LDS ring ----------
#define KSPLIT   4
#define BKQ      32
#define KPS      (KDIM / KSPLIT)               // 2304 K per split
#define NKT      (KPS / BKQ)                   // 72 K-tiles per block
#define NGBLK    ((BATCH / 256) * (OUT_DIM / 256) * KSPLIT)  // 16*4*4 = 256

typedef _Float16 f16x8  __attribute__((ext_vector_type(8)));
typedef float    f32x4  __attribute__((ext_vector_type(4)));

static __device__ __forceinline__ unsigned short f2h_bits(float f) {
  _Float16 h = (_Float16)f;
  return __builtin_bit_cast(unsigned short, h);
}

// async 16B/lane global->LDS copy; LDS dest is wave-uniform base + lane*16
static __device__ __forceinline__ void gl_lds16(const unsigned short* g, unsigned short* l) {
  __builtin_amdgcn_global_load_lds(
      (const __attribute__((address_space(1))) unsigned int*)g,
      (__attribute__((address_space(3))) unsigned int*)l, 16, 0, 0);
}

// ---- kernel 1: fused prep (A path + W path in one launch) — UNCHANGED ------
__global__ __launch_bounds__(256) void prep_k(const float* __restrict__ x,
                                              const float* __restrict__ coeffs,
                                              const float* __restrict__ bw,
                                              const float* __restrict__ gsl,
                                              const float* __restrict__ gstart,
                                              const float* __restrict__ rsp,
                                              unsigned short* __restrict__ A,
                                              unsigned short* __restrict__ W,
                                              float* __restrict__ out) {
  const int blk = blockIdx.x;
  if (blk < NBLK_A) {
    const int i  = (blk & 3) * 256 + threadIdx.x;
    const int b0 = (blk >> 2) * 16;
    const float rs = rsp[0];
    float g[NK];
    float acc = gstart[i];
    g[0] = acc;
#pragma unroll
    for (int t = 0; t < NK - 1; ++t) {
      float v  = gsl[i * (NK - 1) + t];
      float sp = (v > 20.f) ? v : log1pf(expf(v));  // softplus
      acc += sp;
      g[t + 1] = acc;
    }
    float r[30];
#pragma unroll
    for (int j = 0; j < 11; ++j) r[j]      = 1.f / (g[j + 1] - g[j] + EPS);
#pragma unroll
    for (int j = 0; j < 10; ++j) r[11 + j] = 1.f / (g[j + 2] - g[j] + EPS);
#pragma unroll
    for (int j = 0; j <  9; ++j) r[21 + j] = 1.f / (g[j + 3] - g[j] + EPS);

    for (int bb = 0; bb < 16; ++bb) {
      const int b = b0 + bb;
      float xv = x[(size_t)b * IN_DIM + i];
      float bas[NK - 1];
#pragma unroll
      for (int k = 0; k < NK - 1; ++k)
        bas[k] = (xv >= g[k] && xv < g[k + 1]) ? 1.f : 0.f;
      const int off[3] = {0, 11, 21};
#pragma unroll
      for (int d = 1; d <= 3; ++d) {
#pragma unroll
        for (int k = 0; k < NK - 1 - d; ++k) {
          float left  = (xv - g[k])         * r[off[d - 1] + k];
          float right = (g[k + d + 1] - xv) * r[off[d - 1] + k + 1];
          bas[k] = left * bas[k] + right * bas[k + 1];
        }
      }
      uint4 pack;
      pack.x = (unsigned)f2h_bits(bas[0]) | ((unsigned)f2h_bits(bas[1]) << 16);
      pack.y = (unsigned)f2h_bits(bas[2]) | ((unsigned)f2h_bits(bas[3]) << 16);
      pack.z = (unsigned)f2h_bits(bas[4]) | ((unsigned)f2h_bits(bas[5]) << 16);
      pack.w = (unsigned)f2h_bits(bas[6]) | ((unsigned)f2h_bits(bas[7]) << 16);
      *(uint4*)&A[(size_t)b * KDIM + i * NC] = pack;
      float s = xv / (1.f + expf(-xv));  // silu
      A[(size_t)b * KDIM + KSPLINE + i] = f2h_bits(s);
      out[(size_t)b * OUT_DIM + i] = rs * xv;  // init for gemm's atomic sum
    }
  } else {
    int idx = (blk - NBLK_A) * 256 + threadIdx.x;
    int n  = idx / (KDIM / 4);
    int k4 = (idx - n * (KDIM / 4)) * 4;
    float4 v;
    if (k4 < KSPLINE) v = *(const float4*)&coeffs[(size_t)n * KSPLINE + k4];
    else              v = *(const float4*)&bw[(size_t)n * IN_DIM + (k4 - KSPLINE)];
    ushort4 o;
    o.x = f2h_bits(v.x); o.y = f2h_bits(v.y); o.z = f2h_bits(v.z); o.w = f2h_bits(v.w);
    *(ushort4*)&W[(size_t)n * KDIM + k4] = o;
  }
}

// ---- kernel 2: out += A @ W^T, 256x256 tile, deep pipeline (T1-T5) ---------
// 8 waves (2M x 4N), per-wave C = 128x64 as 8x4 grid of 16x16 tiles,
// mfma_f32_16x16x32_f16. 4-slot LDS ring (BK=32, 128 KB total, 1 block/CU):
// iteration t computes slot t&3 and stages K-tile t+3 into slot (t+3)&3
// (= slot of tile t-1, whose reads finished before the previous barrier).
// Counted vmcnt: 2 tiles (8 loads/thread) stay in flight across barriers;
// s_waitcnt vmcnt(8) retires exactly the next tile's 4 loads (FIFO).
// T2: LDS linear dest + XOR-preswizzled global src, chunk ^= row&3 (16B
// granularity); same XOR on ds_read_b128 -> 4-way residual conflicts.
__global__ __launch_bounds__(512, 2) void gemm_k(const unsigned short* __restrict__ A,
                                                 const unsigned short* __restrict__ W,
                                                 float* __restrict__ out) {
  __shared__ __align__(16) unsigned short As[4][256][BKQ];  // 64 KB
  __shared__ __align__(16) unsigned short Bs[4][256][BKQ];  // 64 KB
  const int tid  = threadIdx.x;
  const int wave = tid >> 6;
  const int lane = tid & 63;

  // T1: XCD-aware decode (256 blocks, 256%8==0 -> simple swizzle is bijective).
  // Each XCD gets one ks slice x 2 bn columns x all 16 bm: B-panel 2.4MB L2-fit.
  const int s  = (blockIdx.x & 7) * 32 + (blockIdx.x >> 3);
  const int ks = s >> 6;
  const int bn = (s >> 4) & 3;
  const int bm = s & 15;

  // staging map: thread t -> row tid>>2 (of 128), 16B chunk tid&3, XOR-preswizzled src
  const int srow = tid >> 2;
  const int scsw = ((tid & 3) ^ (srow & 3)) * 8;
  const unsigned short* aG = A + (size_t)(bm * 256 + srow) * KDIM + (size_t)ks * KPS + scsw;
  const unsigned short* bG = W + (size_t)(bn * 256 + srow) * KDIM + (size_t)ks * KPS + scsw;

#define STAGE(t) do {                                                          \
    const int sl_ = (t) & 3; const int kb_ = (t) * BKQ;                        \
    gl_lds16(aG + kb_,                      &As[sl_][wave * 16][0]);           \
    gl_lds16(aG + (size_t)128 * KDIM + kb_, &As[sl_][128 + wave * 16][0]);     \
    gl_lds16(bG + kb_,                      &Bs[sl_][wave * 16][0]);           \
    gl_lds16(bG + (size_t)128 * KDIM + kb_, &Bs[sl_][128 + wave * 16][0]);     \
  } while (0)

  // fragment map (16x16x32): A row = lane&15, k = (lane>>4)*8 + j
  const int l15 = lane & 15;
  const int kg  = lane >> 4;            // 16B k-chunk 0..3
  const int wm  = (wave >> 2) * 128;    // 2 M-waves
  const int wn  = (wave & 3) * 64;      // 4 N-waves

  f32x4 acc[8][4] = {};

  // prologue: 3 tiles in flight, wait for tile 0 (vmcnt(8) = all but newest 8)
  STAGE(0); STAGE(1); STAGE(2);
  asm volatile("s_waitcnt vmcnt(8)" ::: "memory");
  __builtin_amdgcn_s_barrier();

#pragma unroll 4
  for (int kt = 0; kt < NKT; ++kt) {
    if (kt < NKT - 3) STAGE(kt + 3);     // issue-early: ~3 iters to cover HBM latency
    const unsigned short* as = &As[kt & 3][0][0];
    const unsigned short* bs = &Bs[kt & 3][0][0];
    f16x8 af[8], bf[4];
#pragma unroll
    for (int nt = 0; nt < 4; ++nt) {
      int row = wn + nt * 16 + l15;
      bf[nt] = *(const f16x8*)&bs[row * BKQ + ((kg ^ (row & 3)) * 8)];
    }
#pragma unroll
    for (int mt = 0; mt < 8; ++mt) {
      int row = wm + mt * 16 + l15;
      af[mt] = *(const f16x8*)&as[row * BKQ + ((kg ^ (row & 3)) * 8)];
    }
    __builtin_amdgcn_s_setprio(1);
#pragma unroll
    for (int mt = 0; mt < 8; ++mt)
#pragma unroll
      for (int nt = 0; nt < 4; ++nt)
        acc[mt][nt] = __builtin_amdgcn_mfma_f32_16x16x32_f16(af[mt], bf[nt], acc[mt][nt], 0, 0, 0);
    __builtin_amdgcn_s_setprio(0);
    // counted vmcnt: guarantee tile kt+1 resident; never drain to 0 until tail
    if (kt < NKT - 3)       asm volatile("s_waitcnt vmcnt(8)" ::: "memory");
    else if (kt == NKT - 3) asm volatile("s_waitcnt vmcnt(4)" ::: "memory");
    else if (kt == NKT - 2) asm volatile("s_waitcnt vmcnt(0)" ::: "memory");
    if (kt < NKT - 1) __builtin_amdgcn_s_barrier();
  }
#undef STAGE

  // epilogue: C/D 16x16 layout col=lane&15, row=(lane>>4)*4+reg (m89-verified);
  // atomic K-split accumulation onto out (pre-initialized with rs*x by prep_k)
#pragma unroll
  for (int mt = 0; mt < 8; ++mt) {
#pragma unroll
    for (int reg = 0; reg < 4; ++reg) {
      const int row = bm * 256 + wm + mt * 16 + kg * 4 + reg;
      float* orow = out + (size_t)row * OUT_DIM;
#pragma unroll
      for (int nt = 0; nt < 4; ++nt) {
        const int col = bn * 256 + wn + nt * 16 + l15;
        atomicAdd(&orow[col], acc[mt][nt][reg]);
      }
    }
  }
}

// ---- host-side launch ------------------------------------------------------
extern "C" void kernel_launch(void* const* d_in, const int* in_sizes, int n_in,
                              void* d_out, int out_size, void* d_ws, size_t ws_size,
                              hipStream_t stream) {
  const float* x      = (const float*)d_in[0];  // (4096, 1024) fp32
  const float* coeffs = (const float*)d_in[1];  // (1024, 8192)
  const float* bw     = (const float*)d_in[2];  // (1024, 1024)
  const float* gsl    = (const float*)d_in[3];  // (1024, 11)
  const float* gstart = (const float*)d_in[4];  // (1024, 1)
  const float* rsp    = (const float*)d_in[5];  // (1,)

  // ws layout: A (75.5 MB f16) | W (18.9 MB f16) = 94.4 MB total
  char* ws = (char*)d_ws;
  unsigned short* A  = (unsigned short*)ws;
  unsigned short* W  = (unsigned short*)(ws + (size_t)BATCH * KDIM * 2);
  float*          out = (float*)d_out;

  prep_k<<<NBLK_A + NBLK_W, 256, 0, stream>>>(x, coeffs, bw, gsl, gstart, rsp, A, W, out);
  gemm_k<<<NGBLK, 512, 0, stream>>>(A, W, out);
}

// Round 2
// 248.343 us; speedup vs baseline: 1.0199x; 1.0199x over previous
//
#include <hip/hip_runtime.h>

// ---- problem constants -----------------------------------------------------
#define IN_DIM   1024
#define OUT_DIM  1024
#define BATCH    4096
#define NC       8        // N_COEFFS
#define NK       12       // N_KNOTS
#define KSPLINE  (IN_DIM * NC)      // 8192
#define KDIM     (KSPLINE + IN_DIM) // 9216
#define EPS      1e-8f

#define NBLK_A   ((IN_DIM / 256) * (BATCH / 16))      // 1024 A-builder blocks
#define NBLK_W   ((OUT_DIM * (KDIM / 4)) / 256)       // 9216 W-builder blocks

// ---- gemm geometry: 256x256 tile, 8 waves, BK=32, 4-slot LDS ring ----------
#define KSPLIT   4
#define BKQ      32
#define KPS      (KDIM / KSPLIT)               // 2304 K per split
#define NKT      (KPS / BKQ)                   // 72 K-tiles per block
#define NGBLK    ((BATCH / 256) * (OUT_DIM / 256) * KSPLIT)  // 16*4*4 = 256

// LDS row = 32 halfs = 64 B = 4 x 16B chunks. Read swizzle chunk ^= (row>>1)&3
// -> bank position = 16*(row&1) + 4*(chunk^((row>>1)&3)): 8 distinct positions
// over 16 consecutive rows, uniform 8 dwords/bank per b128 = conflict-free.
// (Round-1 used row&3: only 4 positions -> 4-way conflict, 7.08M cycles.)
#define SWZ(r)   (((r) >> 1) & 3)

typedef _Float16 f16x8  __attribute__((ext_vector_type(8)));
typedef float    f32x4  __attribute__((ext_vector_type(4)));

static __device__ __forceinline__ unsigned short f2h_bits(float f) {
  _Float16 h = (_Float16)f;
  return __builtin_bit_cast(unsigned short, h);
}

// async 16B/lane global->LDS copy; LDS dest is wave-uniform base + lane*16
static __device__ __forceinline__ void gl_lds16(const unsigned short* g, unsigned short* l) {
  __builtin_amdgcn_global_load_lds(
      (const __attribute__((address_space(1))) unsigned int*)g,
      (__attribute__((address_space(3))) unsigned int*)l, 16, 0, 0);
}

// ---- kernel 1: fused prep (A path + W path in one launch) — UNCHANGED ------
__global__ __launch_bounds__(256) void prep_k(const float* __restrict__ x,
                                              const float* __restrict__ coeffs,
                                              const float* __restrict__ bw,
                                              const float* __restrict__ gsl,
                                              const float* __restrict__ gstart,
                                              const float* __restrict__ rsp,
                                              unsigned short* __restrict__ A,
                                              unsigned short* __restrict__ W,
                                              float* __restrict__ out) {
  const int blk = blockIdx.x;
  if (blk < NBLK_A) {
    const int i  = (blk & 3) * 256 + threadIdx.x;
    const int b0 = (blk >> 2) * 16;
    const float rs = rsp[0];
    float g[NK];
    float acc = gstart[i];
    g[0] = acc;
#pragma unroll
    for (int t = 0; t < NK - 1; ++t) {
      float v  = gsl[i * (NK - 1) + t];
      float sp = (v > 20.f) ? v : log1pf(expf(v));  // softplus
      acc += sp;
      g[t + 1] = acc;
    }
    float r[30];
#pragma unroll
    for (int j = 0; j < 11; ++j) r[j]      = 1.f / (g[j + 1] - g[j] + EPS);
#pragma unroll
    for (int j = 0; j < 10; ++j) r[11 + j] = 1.f / (g[j + 2] - g[j] + EPS);
#pragma unroll
    for (int j = 0; j <  9; ++j) r[21 + j] = 1.f / (g[j + 3] - g[j] + EPS);

    for (int bb = 0; bb < 16; ++bb) {
      const int b = b0 + bb;
      float xv = x[(size_t)b * IN_DIM + i];
      float bas[NK - 1];
#pragma unroll
      for (int k = 0; k < NK - 1; ++k)
        bas[k] = (xv >= g[k] && xv < g[k + 1]) ? 1.f : 0.f;
      const int off[3] = {0, 11, 21};
#pragma unroll
      for (int d = 1; d <= 3; ++d) {
#pragma unroll
        for (int k = 0; k < NK - 1 - d; ++k) {
          float left  = (xv - g[k])         * r[off[d - 1] + k];
          float right = (g[k + d + 1] - xv) * r[off[d - 1] + k + 1];
          bas[k] = left * bas[k] + right * bas[k + 1];
        }
      }
      uint4 pack;
      pack.x = (unsigned)f2h_bits(bas[0]) | ((unsigned)f2h_bits(bas[1]) << 16);
      pack.y = (unsigned)f2h_bits(bas[2]) | ((unsigned)f2h_bits(bas[3]) << 16);
      pack.z = (unsigned)f2h_bits(bas[4]) | ((unsigned)f2h_bits(bas[5]) << 16);
      pack.w = (unsigned)f2h_bits(bas[6]) | ((unsigned)f2h_bits(bas[7]) << 16);
      *(uint4*)&A[(size_t)b * KDIM + i * NC] = pack;
      float s = xv / (1.f + expf(-xv));  // silu
      A[(size_t)b * KDIM + KSPLINE + i] = f2h_bits(s);
      out[(size_t)b * OUT_DIM + i] = rs * xv;  // init for gemm's atomic sum
    }
  } else {
    int idx = (blk - NBLK_A) * 256 + threadIdx.x;
    int n  = idx / (KDIM / 4);
    int k4 = (idx - n * (KDIM / 4)) * 4;
    float4 v;
    if (k4 < KSPLINE) v = *(const float4*)&coeffs[(size_t)n * KSPLINE + k4];
    else              v = *(const float4*)&bw[(size_t)n * IN_DIM + (k4 - KSPLINE)];
    ushort4 o;
    o.x = f2h_bits(v.x); o.y = f2h_bits(v.y); o.z = f2h_bits(v.z); o.w = f2h_bits(v.w);
    *(ushort4*)&W[(size_t)n * KDIM + k4] = o;
  }
}

// ---- kernel 2: out += A @ W^T, 256x256 tile, 2-phase/K-tile pipeline -------
// 8 waves (2M x 4N), per-wave C = 128x64 = 8x4 grid of 16x16, mfma 16x16x32.
// 4-slot LDS ring (BK=32, 128 KB, 1 block/CU). Per K-tile, TWO 16-MFMA phases
// (m201 granularity: ~16 MFMA + 4-8 ds_read + 2 gl_lds + 2 barriers/phase):
//   phase A: read af[0-3],bf[0-3] (8 b128) | stage A(kt+3) | bar | 16 MFMA | bar
//   phase B: read af[4-7]          (4 b128) | stage B(kt+3) | bar | 16 MFMA |
//            vmcnt(8) | bar
// Counted vmcnt (T4): 12 loads outstanding, vmcnt(8) retires exactly tile
// kt+1's 4 (FIFO); placed BEFORE the final barrier so every wave's stages for
// kt+1 have landed before any wave reads them. Never drains in main loop
// (tail: 8 -> 4 -> 0). Slot (kt+3)&3 == (kt-1)&3: its last reads retired
// before kt-1's final MFMA cluster, hence before any kt-phase stage issues.
__global__ __launch_bounds__(512, 2) void gemm_k(const unsigned short* __restrict__ A,
                                                 const unsigned short* __restrict__ W,
                                                 float* __restrict__ out) {
  __shared__ __align__(16) unsigned short As[4][256][BKQ];  // 64 KB
  __shared__ __align__(16) unsigned short Bs[4][256][BKQ];  // 64 KB
  const int tid  = threadIdx.x;
  const int wave = tid >> 6;
  const int lane = tid & 63;

  // T1: XCD-aware decode (256 blocks % 8 == 0 -> bijective). Each XCD owns one
  // ks slice x 2 bn columns x all 16 bm: B-panel 2.4 MB L2-fit (FETCH 111->83MB).
  const int s  = (blockIdx.x & 7) * 32 + (blockIdx.x >> 3);
  const int ks = s >> 6;
  const int bn = (s >> 4) & 3;
  const int bm = s & 15;

  // staging: thread t -> LDS row tid>>2 (+128 on 2nd call), 16B chunk tid&3.
  // Source chunk pre-swizzled by the SAME involution the reads apply (rule #21):
  // LDS[row][c] holds global[row][c ^ SWZ(row)]. SWZ(row+128)==SWZ(row).
  const int srow = tid >> 2;
  const int scsw = ((tid & 3) ^ SWZ(srow)) * 8;
  const unsigned short* aG = A + (size_t)(bm * 256 + srow) * KDIM + (size_t)ks * KPS + scsw;
  const unsigned short* bG = W + (size_t)(bn * 256 + srow) * KDIM + (size_t)ks * KPS + scsw;

#define STAGE_A(t) do {                                                        \
    const int sl_ = (t) & 3; const int kb_ = (t) * BKQ;                        \
    gl_lds16(aG + kb_,                      &As[sl_][wave * 16][0]);           \
    gl_lds16(aG + (size_t)128 * KDIM + kb_, &As[sl_][128 + wave * 16][0]);     \
  } while (0)
#define STAGE_B(t) do {                                                        \
    const int sl_ = (t) & 3; const int kb_ = (t) * BKQ;                        \
    gl_lds16(bG + kb_,                      &Bs[sl_][wave * 16][0]);           \
    gl_lds16(bG + (size_t)128 * KDIM + kb_, &Bs[sl_][128 + wave * 16][0]);     \
  } while (0)

  // fragment map (16x16x32): row = lane&15, k-chunk kg = lane>>4 (8 halfs)
  const int l15 = lane & 15;
  const int kg  = lane >> 4;
  const int wm  = (wave >> 2) * 128;    // 2 M-wave groups
  const int wn  = (wave & 3) * 64;      // 4 N-wave groups

  f32x4 acc[8][4] = {};

  // prologue: tiles 0,1,2 in flight (12 loads); vmcnt(8) -> tile 0 resident
  STAGE_A(0); STAGE_B(0); STAGE_A(1); STAGE_B(1); STAGE_A(2); STAGE_B(2);
  asm volatile("s_waitcnt vmcnt(8)" ::: "memory");
  __builtin_amdgcn_s_barrier();

#pragma unroll 4
  for (int kt = 0; kt < NKT; ++kt) {
    const unsigned short* as = &As[kt & 3][0][0];
    const unsigned short* bs = &Bs[kt & 3][0][0];
    f16x8 af[4], bf[4];

    // ---------------- phase A: quadrant mt0-3 x nt0-3 ----------------------
#pragma unroll
    for (int mt = 0; mt < 4; ++mt) {
      int row = wm + mt * 16 + l15;
      af[mt] = *(const f16x8*)&as[row * BKQ + ((kg ^ SWZ(row)) * 8)];
    }
#pragma unroll
    for (int nt = 0; nt < 4; ++nt) {
      int row = wn + nt * 16 + l15;
      bf[nt] = *(const f16x8*)&bs[row * BKQ + ((kg ^ SWZ(row)) * 8)];
    }
    if (kt < NKT - 3) STAGE_A(kt + 3);
    __builtin_amdgcn_s_barrier();
    __builtin_amdgcn_s_setprio(1);
#pragma unroll
    for (int mt = 0; mt < 4; ++mt)
#pragma unroll
      for (int nt = 0; nt < 4; ++nt)
        acc[mt][nt] = __builtin_amdgcn_mfma_f32_16x16x32_f16(af[mt], bf[nt], acc[mt][nt], 0, 0, 0);
    __builtin_amdgcn_s_setprio(0);
    __builtin_amdgcn_s_barrier();

    // ---------------- phase B: quadrant mt4-7 x nt0-3 (bf reused) ----------
#pragma unroll
    for (int mt = 0; mt < 4; ++mt) {
      int row = wm + 64 + mt * 16 + l15;
      af[mt] = *(const f16x8*)&as[row * BKQ + ((kg ^ SWZ(row)) * 8)];
    }
    if (kt < NKT - 3) STAGE_B(kt + 3);
    __builtin_amdgcn_s_barrier();
    __builtin_amdgcn_s_setprio(1);
#pragma unroll
    for (int mt = 0; mt < 4; ++mt)
#pragma unroll
      for (int nt = 0; nt < 4; ++nt)
        acc[4 + mt][nt] = __builtin_amdgcn_mfma_f32_16x16x32_f16(af[mt], bf[nt], acc[4 + mt][nt], 0, 0, 0);
    __builtin_amdgcn_s_setprio(0);
    // counted vmcnt BEFORE the slot-transition barrier: after the barrier all
    // waves' tile-(kt+1) stages have landed; 8 loads (2 tiles) stay in flight.
    if (kt < NKT - 3)       asm volatile("s_waitcnt vmcnt(8)" ::: "memory");
    else if (kt == NKT - 3) asm volatile("s_waitcnt vmcnt(4)" ::: "memory");
    else if (kt == NKT - 2) asm volatile("s_waitcnt vmcnt(0)" ::: "memory");
    if (kt < NKT - 1) __builtin_amdgcn_s_barrier();
  }
#undef STAGE_A
#undef STAGE_B

  // epilogue: C/D 16x16 layout col=lane&15, row=(lane>>4)*4+reg (m89-verified);
  // atomic K-split accumulation onto out (pre-initialized with rs*x by prep_k)
#pragma unroll
  for (int mt = 0; mt < 8; ++mt) {
#pragma unroll
    for (int reg = 0; reg < 4; ++reg) {
      const int row = bm * 256 + wm + mt * 16 + kg * 4 + reg;
      float* orow = out + (size_t)row * OUT_DIM;
#pragma unroll
      for (int nt = 0; nt < 4; ++nt) {
        const int col = bn * 256 + wn + nt * 16 + l15;
        atomicAdd(&orow[col], acc[mt][nt][reg]);
      }
    }
  }
}

// ---- host-side launch ------------------------------------------------------
extern "C" void kernel_launch(void* const* d_in, const int* in_sizes, int n_in,
                              void* d_out, int out_size, void* d_ws, size_t ws_size,
                              hipStream_t stream) {
  const float* x      = (const float*)d_in[0];  // (4096, 1024) fp32
  const float* coeffs = (const float*)d_in[1];  // (1024, 8192)
  const float* bw     = (const float*)d_in[2];  // (1024, 1024)
  const float* gsl    = (const float*)d_in[3];  // (1024, 11)
  const float* gstart = (const float*)d_in[4];  // (1024, 1)
  const float* rsp    = (const float*)d_in[5];  // (1,)

  // ws layout: A (75.5 MB f16) | W (18.9 MB f16) = 94.4 MB total
  char* ws = (char*)d_ws;
  unsigned short* A  = (unsigned short*)ws;
  unsigned short* W  = (unsigned short*)(ws + (size_t)BATCH * KDIM * 2);
  float*          out = (float*)d_out;

  prep_k<<<NBLK_A + NBLK_W, 256, 0, stream>>>(x, coeffs, bw, gsl, gstart, rsp, A, W, out);
  gemm_k<<<NGBLK, 512, 0, stream>>>(A, W, out);
}

// Round 3
// 247.496 us; speedup vs baseline: 1.0234x; 1.0034x over previous
//
#include <hip/hip_runtime.h>

// ---- problem constants -----------------------------------------------------
#define IN_DIM   1024
#define OUT_DIM  1024
#define BATCH    4096
#define NC       8        // N_COEFFS
#define NK       12       // N_KNOTS
#define KSPLINE  (IN_DIM * NC)      // 8192
#define KDIM     (KSPLINE + IN_DIM) // 9216
#define EPS      1e-8f

#define NBLK_A   ((IN_DIM / 256) * (BATCH / 16))      // 1024 A-builder blocks
#define NBLK_W   ((OUT_DIM * (KDIM / 4)) / 256)       // 9216 W-builder blocks

// ---- gemm geometry: 128x64 tile, 4 waves, KSPLIT=1 (NO atomics) ------------
// Round0 (128^2) and Round2 (256^2, deep pipe) both hit ~120us: shared term =
// 16.8M-atomicAdd K-split tail (WRITE=4x output both rounds). Fix: grid =
// exactly the 32x16 output tiles = 512 blocks (2/CU), full K per block.
#define BM       128
#define BN       64
#define BKQ      32
#define NKT      (KDIM / BKQ)                  // 288 K-tiles
#define NGBLK    ((BATCH / BM) * (OUT_DIM / BN))  // 512

// LDS row = 32 halfs = 64 B = 4 x 16B chunks. Read chunk ^= (row>>1)&3 ->
// bank pos = 16*(row&1)+4*(chunk^((row>>1)&3)): 16 lanes -> 2 lanes/bank-quad
// = free (m136). Verified: SQ_LDS_BANK_CONFLICT == 0 in round 2.
#define SWZ(r)   (((r) >> 1) & 3)

typedef _Float16 f16x8  __attribute__((ext_vector_type(8)));
typedef float    f32x4  __attribute__((ext_vector_type(4)));

static __device__ __forceinline__ unsigned short f2h_bits(float f) {
  _Float16 h = (_Float16)f;
  return __builtin_bit_cast(unsigned short, h);
}

// async 16B/lane global->LDS copy; LDS dest is wave-uniform base + lane*16
static __device__ __forceinline__ void gl_lds16(const unsigned short* g, unsigned short* l) {
  __builtin_amdgcn_global_load_lds(
      (const __attribute__((address_space(1))) unsigned int*)g,
      (__attribute__((address_space(3))) unsigned int*)l, 16, 0, 0);
}

// ---- kernel 1: fused prep (A path + W path in one launch) — UNCHANGED ------
__global__ __launch_bounds__(256) void prep_k(const float* __restrict__ x,
                                              const float* __restrict__ coeffs,
                                              const float* __restrict__ bw,
                                              const float* __restrict__ gsl,
                                              const float* __restrict__ gstart,
                                              const float* __restrict__ rsp,
                                              unsigned short* __restrict__ A,
                                              unsigned short* __restrict__ W,
                                              float* __restrict__ out) {
  const int blk = blockIdx.x;
  if (blk < NBLK_A) {
    const int i  = (blk & 3) * 256 + threadIdx.x;
    const int b0 = (blk >> 2) * 16;
    const float rs = rsp[0];
    float g[NK];
    float acc = gstart[i];
    g[0] = acc;
#pragma unroll
    for (int t = 0; t < NK - 1; ++t) {
      float v  = gsl[i * (NK - 1) + t];
      float sp = (v > 20.f) ? v : log1pf(expf(v));  // softplus
      acc += sp;
      g[t + 1] = acc;
    }
    float r[30];
#pragma unroll
    for (int j = 0; j < 11; ++j) r[j]      = 1.f / (g[j + 1] - g[j] + EPS);
#pragma unroll
    for (int j = 0; j < 10; ++j) r[11 + j] = 1.f / (g[j + 2] - g[j] + EPS);
#pragma unroll
    for (int j = 0; j <  9; ++j) r[21 + j] = 1.f / (g[j + 3] - g[j] + EPS);

    for (int bb = 0; bb < 16; ++bb) {
      const int b = b0 + bb;
      float xv = x[(size_t)b * IN_DIM + i];
      float bas[NK - 1];
#pragma unroll
      for (int k = 0; k < NK - 1; ++k)
        bas[k] = (xv >= g[k] && xv < g[k + 1]) ? 1.f : 0.f;
      const int off[3] = {0, 11, 21};
#pragma unroll
      for (int d = 1; d <= 3; ++d) {
#pragma unroll
        for (int k = 0; k < NK - 1 - d; ++k) {
          float left  = (xv - g[k])         * r[off[d - 1] + k];
          float right = (g[k + d + 1] - xv) * r[off[d - 1] + k + 1];
          bas[k] = left * bas[k] + right * bas[k + 1];
        }
      }
      uint4 pack;
      pack.x = (unsigned)f2h_bits(bas[0]) | ((unsigned)f2h_bits(bas[1]) << 16);
      pack.y = (unsigned)f2h_bits(bas[2]) | ((unsigned)f2h_bits(bas[3]) << 16);
      pack.z = (unsigned)f2h_bits(bas[4]) | ((unsigned)f2h_bits(bas[5]) << 16);
      pack.w = (unsigned)f2h_bits(bas[6]) | ((unsigned)f2h_bits(bas[7]) << 16);
      *(uint4*)&A[(size_t)b * KDIM + i * NC] = pack;
      float s = xv / (1.f + expf(-xv));  // silu
      A[(size_t)b * KDIM + KSPLINE + i] = f2h_bits(s);
      out[(size_t)b * OUT_DIM + i] = rs * xv;  // init for gemm's += epilogue
    }
  } else {
    int idx = (blk - NBLK_A) * 256 + threadIdx.x;
    int n  = idx / (KDIM / 4);
    int k4 = (idx - n * (KDIM / 4)) * 4;
    float4 v;
    if (k4 < KSPLINE) v = *(const float4*)&coeffs[(size_t)n * KSPLINE + k4];
    else              v = *(const float4*)&bw[(size_t)n * IN_DIM + (k4 - KSPLINE)];
    ushort4 o;
    o.x = f2h_bits(v.x); o.y = f2h_bits(v.y); o.z = f2h_bits(v.z); o.w = f2h_bits(v.w);
    *(ushort4*)&W[(size_t)n * KDIM + k4] = o;
  }
}

// ---- kernel 2: out += A @ W^T, 128x64 tile, full-K, atomic-free ------------
// 4 waves (2M x 2N), wave-tile 64x32 = 4x2 grid of 16x16, mfma 16x16x32_f16.
// 4-slot LDS ring (BK=32, 48 KB -> 2 blocks/CU): two co-resident blocks have
// INDEPENDENT barrier domains, so block A's MFMA burst overlaps block B's
// ds_read/stage window (m97/m114 implicit-overlap mechanism) — no intra-block
// scheduling heroics needed.
// ONE barrier per K-tile: tile-kt residency is published by iter kt-1's
// counted vmcnt + barrier; slot (kt+3)&3 == (kt-1)&3 is reusable because all
// waves' tile-(kt-1) ds_reads completed (lgkm) before their iter-(kt-1) MFMAs,
// which precede that barrier. Counted vmcnt (T4): 3 gl_lds per STAGE; steady
// state vmcnt(6) = 2 tiles in flight; tail drains 6 -> 3 -> 0.
__global__ __launch_bounds__(256, 2) void gemm_k(const unsigned short* __restrict__ A,
                                                 const unsigned short* __restrict__ W,
                                                 float* __restrict__ out) {
  __shared__ __align__(16) unsigned short As[4][BM][BKQ];  // 32 KB
  __shared__ __align__(16) unsigned short Bs[4][BN][BKQ];  // 16 KB
  const int tid  = threadIdx.x;
  const int wave = tid >> 6;
  const int lane = tid & 63;

  // T1: XCD decode, bm-major grouping: XCD x owns bm in [4x, 4x+4) x all 16 bn
  // -> per-XCD L2 miss ~ 4 A-panels (9.4 MB stream) + B K-slices; B-slice reuse
  // by 4 bm-blocks in-XCD. 512 % 8 == 0 -> bijective.
  const int xcd = blockIdx.x & 7;
  const int idx = blockIdx.x >> 3;           // 0..63
  const int bm  = xcd * 4 + (idx & 3);       // 0..31
  const int bn  = idx >> 2;                  // 0..15

  // staging: thread -> row wave*16 + (lane>>2), 16B chunk lane&3, source
  // pre-swizzled by the same involution the reads apply (rule #21).
  // SWZ(row) == SWZ(row+64), so one swizzled base serves both A halves.
  const int srow = wave * 16 + (lane >> 2);
  const int scsw = ((lane & 3) ^ SWZ(srow)) * 8;
  const unsigned short* aG = A + (size_t)(bm * BM + srow) * KDIM + scsw;
  const unsigned short* bG = W + (size_t)(bn * BN + srow) * KDIM + scsw;

#define STAGE(t) do {                                                          \
    const int sl_ = (t) & 3; const int kb_ = (t) * BKQ;                        \
    gl_lds16(aG + kb_,                     &As[sl_][wave * 16][0]);            \
    gl_lds16(aG + (size_t)64 * KDIM + kb_, &As[sl_][64 + wave * 16][0]);       \
    gl_lds16(bG + kb_,                     &Bs[sl_][wave * 16][0]);            \
  } while (0)

  // fragment map (16x16x32): row = lane&15, k-chunk kg = lane>>4 (8 halfs)
  const int l15 = lane & 15;
  const int kg  = lane >> 4;
  const int wm  = (wave >> 1) * 64;     // 2 M-wave groups
  const int wn  = (wave & 1) * 32;      // 2 N-wave groups

  f32x4 acc[4][2] = {};

  // prologue: tiles 0,1,2 in flight (9 loads/wave); vmcnt(6) -> tile 0 landed;
  // barrier publishes all waves' tile-0 stages.
  STAGE(0); STAGE(1); STAGE(2);
  asm volatile("s_waitcnt vmcnt(6)" ::: "memory");
  __builtin_amdgcn_s_barrier();

#pragma unroll 4
  for (int kt = 0; kt < NKT; ++kt) {
    const unsigned short* as = &As[kt & 3][0][0];
    const unsigned short* bs = &Bs[kt & 3][0][0];
    f16x8 af[4], bf[2];
#pragma unroll
    for (int mt = 0; mt < 4; ++mt) {
      int row = wm + mt * 16 + l15;
      af[mt] = *(const f16x8*)&as[row * BKQ + ((kg ^ SWZ(row)) * 8)];
    }
#pragma unroll
    for (int nt = 0; nt < 2; ++nt) {
      int row = wn + nt * 16 + l15;
      bf[nt] = *(const f16x8*)&bs[row * BKQ + ((kg ^ SWZ(row)) * 8)];
    }
    if (kt < NKT - 3) STAGE(kt + 3);     // issue-early; lands under ~3 iters of compute
    __builtin_amdgcn_sched_barrier(0);   // pin load issue before the MFMA region
    __builtin_amdgcn_s_setprio(1);
#pragma unroll
    for (int mt = 0; mt < 4; ++mt)
#pragma unroll
      for (int nt = 0; nt < 2; ++nt)
        acc[mt][nt] = __builtin_amdgcn_mfma_f32_16x16x32_f16(af[mt], bf[nt], acc[mt][nt], 0, 0, 0);
    __builtin_amdgcn_s_setprio(0);
    // counted vmcnt BEFORE the slot-transition barrier: tile kt+1 resident for
    // everyone after the barrier; 2 tiles (6 loads) stay in flight.
    if (kt < NKT - 3)       asm volatile("s_waitcnt vmcnt(6)" ::: "memory");
    else if (kt == NKT - 3) asm volatile("s_waitcnt vmcnt(3)" ::: "memory");
    else if (kt == NKT - 2) asm volatile("s_waitcnt vmcnt(0)" ::: "memory");
    if (kt < NKT - 1) __builtin_amdgcn_s_barrier();
  }
#undef STAGE

  // epilogue: C/D 16x16 layout col=lane&15, row=(lane>>4)*4+reg (m89-verified).
  // Block owns its 128x64 tile exclusively -> plain RMW, zero atomics.
#pragma unroll
  for (int mt = 0; mt < 4; ++mt) {
#pragma unroll
    for (int reg = 0; reg < 4; ++reg) {
      const int row = bm * BM + wm + mt * 16 + kg * 4 + reg;
      float* orow = out + (size_t)row * OUT_DIM;
#pragma unroll
      for (int nt = 0; nt < 2; ++nt) {
        const int col = bn * BN + wn + nt * 16 + l15;
        orow[col] += acc[mt][nt][reg];
      }
    }
  }
}

// ---- host-side launch ------------------------------------------------------
extern "C" void kernel_launch(void* const* d_in, const int* in_sizes, int n_in,
                              void* d_out, int out_size, void* d_ws, size_t ws_size,
                              hipStream_t stream) {
  const float* x      = (const float*)d_in[0];  // (4096, 1024) fp32
  const float* coeffs = (const float*)d_in[1];  // (1024, 8192)
  const float* bw     = (const float*)d_in[2];  // (1024, 1024)
  const float* gsl    = (const float*)d_in[3];  // (1024, 11)
  const float* gstart = (const float*)d_in[4];  // (1024, 1)
  const float* rsp    = (const float*)d_in[5];  // (1,)

  // ws layout: A (75.5 MB f16) | W (18.9 MB f16) = 94.4 MB total
  char* ws = (char*)d_ws;
  unsigned short* A  = (unsigned short*)ws;
  unsigned short* W  = (unsigned short*)(ws + (size_t)BATCH * KDIM * 2);
  float*          out = (float*)d_out;

  prep_k<<<NBLK_A + NBLK_W, 256, 0, stream>>>(x, coeffs, bw, gsl, gstart, rsp, A, W, out);
  gemm_k<<<NGBLK, 256, 0, stream>>>(A, W, out);
}

// Round 4
// 241.390 us; speedup vs baseline: 1.0493x; 1.0253x over previous
//
#include <hip/hip_runtime.h>

// ---- problem constants -----------------------------------------------------
#define IN_DIM   1024
#define OUT_DIM  1024
#define BATCH    4096
#define NC       8        // N_COEFFS
#define NK       12       // N_KNOTS
#define KSPLINE  (IN_DIM * NC)      // 8192
#define KDIM     (KSPLINE + IN_DIM) // 9216
#define EPS      1e-8f

#define NBLK_A   ((IN_DIM / 256) * (BATCH / 16))      // 1024 A-builder blocks
#define NBLK_W   ((OUT_DIM * (KDIM / 4)) / 256)       // 9216 W-builder blocks

// ---- gemm geometry: 256x128 tile, 8 waves, KSPLIT=2, partial+reduce --------
// Model from rounds 2/3: gemm time scales with per-CU ds_read/MFMA volume
// (~16-21 cyc per ds_read_b128 effective), so raise FLOP-per-read: wave-tile
// 64x64 -> 8 reads / 16 MFMA per K-tile (ratio 2.0 vs round-3's 1.33), and
// KSPLIT=2 halves per-block iterations (144) while keeping 256 blocks = 1/CU.
#define BM       256
#define BN       128
#define BKQ      32
#define KSPLIT   2
#define KPS      (KDIM / KSPLIT)               // 4608
#define NKT      (KPS / BKQ)                   // 144 K-tiles per block
#define NGBLK    ((BATCH / BM) * (OUT_DIM / BN) * KSPLIT)  // 16*8*2 = 256

// LDS row = 32 halfs = 64 B = 4 x 16B chunks. Read chunk ^= (row>>1)&3 ->
// 16 lanes spread over 8 bank-quad positions = 2/quad = free (m136).
// Verified 0 conflicts in rounds 2-3.
#define SWZ(r)   (((r) >> 1) & 3)

typedef _Float16 f16x8  __attribute__((ext_vector_type(8)));
typedef float    f32x4  __attribute__((ext_vector_type(4)));

static __device__ __forceinline__ unsigned short f2h_bits(float f) {
  _Float16 h = (_Float16)f;
  return __builtin_bit_cast(unsigned short, h);
}

// async 16B/lane global->LDS copy; LDS dest is wave-uniform base + lane*16
static __device__ __forceinline__ void gl_lds16(const unsigned short* g, unsigned short* l) {
  __builtin_amdgcn_global_load_lds(
      (const __attribute__((address_space(1))) unsigned int*)g,
      (__attribute__((address_space(3))) unsigned int*)l, 16, 0, 0);
}

// ---- kernel 1: fused prep (A path + W path) — bb loop unrolled x4 ----------
__global__ __launch_bounds__(256) void prep_k(const float* __restrict__ x,
                                              const float* __restrict__ coeffs,
                                              const float* __restrict__ bw,
                                              const float* __restrict__ gsl,
                                              const float* __restrict__ gstart,
                                              const float* __restrict__ rsp,
                                              unsigned short* __restrict__ A,
                                              unsigned short* __restrict__ W,
                                              float* __restrict__ out) {
  const int blk = blockIdx.x;
  if (blk < NBLK_A) {
    const int i  = (blk & 3) * 256 + threadIdx.x;
    const int b0 = (blk >> 2) * 16;
    const float rs = rsp[0];
    float g[NK];
    float acc = gstart[i];
    g[0] = acc;
#pragma unroll
    for (int t = 0; t < NK - 1; ++t) {
      float v  = gsl[i * (NK - 1) + t];
      float sp = (v > 20.f) ? v : log1pf(expf(v));  // softplus
      acc += sp;
      g[t + 1] = acc;
    }
    float r[30];
#pragma unroll
    for (int j = 0; j < 11; ++j) r[j]      = 1.f / (g[j + 1] - g[j] + EPS);
#pragma unroll
    for (int j = 0; j < 10; ++j) r[11 + j] = 1.f / (g[j + 2] - g[j] + EPS);
#pragma unroll
    for (int j = 0; j <  9; ++j) r[21 + j] = 1.f / (g[j + 3] - g[j] + EPS);

#pragma unroll 4
    for (int bb = 0; bb < 16; ++bb) {
      const int b = b0 + bb;
      float xv = x[(size_t)b * IN_DIM + i];
      float bas[NK - 1];
#pragma unroll
      for (int k = 0; k < NK - 1; ++k)
        bas[k] = (xv >= g[k] && xv < g[k + 1]) ? 1.f : 0.f;
      const int off[3] = {0, 11, 21};
#pragma unroll
      for (int d = 1; d <= 3; ++d) {
#pragma unroll
        for (int k = 0; k < NK - 1 - d; ++k) {
          float left  = (xv - g[k])         * r[off[d - 1] + k];
          float right = (g[k + d + 1] - xv) * r[off[d - 1] + k + 1];
          bas[k] = left * bas[k] + right * bas[k + 1];
        }
      }
      uint4 pack;
      pack.x = (unsigned)f2h_bits(bas[0]) | ((unsigned)f2h_bits(bas[1]) << 16);
      pack.y = (unsigned)f2h_bits(bas[2]) | ((unsigned)f2h_bits(bas[3]) << 16);
      pack.z = (unsigned)f2h_bits(bas[4]) | ((unsigned)f2h_bits(bas[5]) << 16);
      pack.w = (unsigned)f2h_bits(bas[6]) | ((unsigned)f2h_bits(bas[7]) << 16);
      *(uint4*)&A[(size_t)b * KDIM + i * NC] = pack;
      float s = xv / (1.f + expf(-xv));  // silu
      A[(size_t)b * KDIM + KSPLINE + i] = f2h_bits(s);
      out[(size_t)b * OUT_DIM + i] = rs * xv;  // init for gemm's += epilogue
    }
  } else {
    int idx = (blk - NBLK_A) * 256 + threadIdx.x;
    int n  = idx / (KDIM / 4);
    int k4 = (idx - n * (KDIM / 4)) * 4;
    float4 v;
    if (k4 < KSPLINE) v = *(const float4*)&coeffs[(size_t)n * KSPLINE + k4];
    else              v = *(const float4*)&bw[(size_t)n * IN_DIM + (k4 - KSPLINE)];
    ushort4 o;
    o.x = f2h_bits(v.x); o.y = f2h_bits(v.y); o.z = f2h_bits(v.z); o.w = f2h_bits(v.w);
    *(ushort4*)&W[(size_t)n * KDIM + k4] = o;
  }
}

// ---- kernel 2: out/P += A @ W^T, 256x128 tile, K-split x2, no atomics ------
// 8 waves (4M x 2N), wave-tile 64x64 = 4x4 grid of 16x16, mfma 16x16x32_f16.
// 4-slot LDS ring (BK=32, 96 KB, 1 block/CU). ONE barrier per K-tile:
// tile-kt residency published by iter kt-1's counted vmcnt + barrier; slot
// (kt+3)&3 == (kt-1)&3 reusable since all waves' kt-1 ds_reads retired (lgkm)
// before their kt-1 MFMAs, which precede that barrier. Counted vmcnt (T4):
// 3 gl_lds/STAGE, steady vmcnt(6) = 2 tiles in flight; tail 6 -> 3 -> 0.
// K-split accumulation: ks=0 blocks += into out (pre-init rs*x), ks=1 blocks
// plain-store partial P; reduce_k folds P in. No atomics anywhere (fallback:
// if ws can't hold P, both slices atomicAdd).
__global__ __launch_bounds__(512, 2) void gemm_k(const unsigned short* __restrict__ A,
                                                 const unsigned short* __restrict__ W,
                                                 float* __restrict__ out,
                                                 float* __restrict__ P,
                                                 int use_partial) {
  __shared__ __align__(16) unsigned short As[4][BM][BKQ];  // 64 KB
  __shared__ __align__(16) unsigned short Bs[4][BN][BKQ];  // 32 KB
  const int tid  = threadIdx.x;
  const int wave = tid >> 6;
  const int lane = tid & 63;

  // T1: XCD decode (256 % 8 == 0 -> bijective). XCD x owns one ks slice x
  // 2 bn columns x all 16 bm: B-slice 2.4 MB L2-resident, A-panels reused x2.
  const int s  = (blockIdx.x & 7) * 32 + (blockIdx.x >> 3);
  const int ks = s >> 7;                     // 0..1
  const int bn = (s >> 4) & 7;               // 0..7
  const int bm = s & 15;                     // 0..15

  // staging: thread -> row tid>>2 (0..127), 16B chunk tid&3; source chunk
  // pre-XOR'd by the same involution the reads apply (rule #21).
  // SWZ(row+128) == SWZ(row), so one swizzled base serves both A sweeps.
  const int srow = tid >> 2;
  const int scsw = ((tid & 3) ^ SWZ(srow)) * 8;
  const unsigned short* aG = A + (size_t)(bm * BM + srow) * KDIM + (size_t)ks * KPS + scsw;
  const unsigned short* bG = W + (size_t)(bn * BN + srow) * KDIM + (size_t)ks * KPS + scsw;

#define STAGE(t) do {                                                          \
    const int sl_ = (t) & 3; const int kb_ = (t) * BKQ;                        \
    gl_lds16(aG + kb_,                      &As[sl_][wave * 16][0]);           \
    gl_lds16(aG + (size_t)128 * KDIM + kb_, &As[sl_][128 + wave * 16][0]);     \
    gl_lds16(bG + kb_,                      &Bs[sl_][wave * 16][0]);           \
  } while (0)

  // fragment map (16x16x32): row = lane&15, k-chunk kg = lane>>4 (8 halfs)
  const int l15 = lane & 15;
  const int kg  = lane >> 4;
  const int wm  = (wave >> 1) * 64;     // 4 M-wave groups
  const int wn  = (wave & 1) * 64;      // 2 N-wave groups

  f32x4 acc[4][4] = {};

  // prologue: tiles 0,1,2 in flight (9 loads/thread); vmcnt(6) -> tile 0
  // landed; barrier publishes all waves' tile-0 stages.
  STAGE(0); STAGE(1); STAGE(2);
  asm volatile("s_waitcnt vmcnt(6)" ::: "memory");
  __builtin_amdgcn_s_barrier();

#pragma unroll 4
  for (int kt = 0; kt < NKT; ++kt) {
    const unsigned short* as = &As[kt & 3][0][0];
    const unsigned short* bs = &Bs[kt & 3][0][0];
    f16x8 af[4], bf[4];
#pragma unroll
    for (int mt = 0; mt < 4; ++mt) {
      int row = wm + mt * 16 + l15;
      af[mt] = *(const f16x8*)&as[row * BKQ + ((kg ^ SWZ(row)) * 8)];
    }
#pragma unroll
    for (int nt = 0; nt < 4; ++nt) {
      int row = wn + nt * 16 + l15;
      bf[nt] = *(const f16x8*)&bs[row * BKQ + ((kg ^ SWZ(row)) * 8)];
    }
    if (kt < NKT - 3) STAGE(kt + 3);     // issue-early; lands in ~3 iters
    __builtin_amdgcn_s_setprio(1);
#pragma unroll
    for (int mt = 0; mt < 4; ++mt)
#pragma unroll
      for (int nt = 0; nt < 4; ++nt)
        acc[mt][nt] = __builtin_amdgcn_mfma_f32_16x16x32_f16(af[mt], bf[nt], acc[mt][nt], 0, 0, 0);
    __builtin_amdgcn_s_setprio(0);
    // counted vmcnt BEFORE the slot-transition barrier: tile kt+1 resident
    // for everyone after the barrier; 2 tiles (6 loads) stay in flight.
    if (kt < NKT - 3)       asm volatile("s_waitcnt vmcnt(6)" ::: "memory");
    else if (kt == NKT - 3) asm volatile("s_waitcnt vmcnt(3)" ::: "memory");
    else if (kt == NKT - 2) asm volatile("s_waitcnt vmcnt(0)" ::: "memory");
    if (kt < NKT - 1) __builtin_amdgcn_s_barrier();
  }
#undef STAGE

  // epilogue: C/D 16x16 layout col=lane&15, row=(lane>>4)*4+reg (m89-verified)
#pragma unroll
  for (int mt = 0; mt < 4; ++mt) {
#pragma unroll
    for (int reg = 0; reg < 4; ++reg) {
      const int row = bm * BM + wm + mt * 16 + kg * 4 + reg;
      const size_t ro = (size_t)row * OUT_DIM;
#pragma unroll
      for (int nt = 0; nt < 4; ++nt) {
        const int col = bn * BN + wn + nt * 16 + l15;
        const float v = acc[mt][nt][reg];
        if (use_partial) {
          if (ks == 0) out[ro + col] += v;   // exclusive owner of slice 0
          else         P[ro + col]    = v;   // plain store, folded by reduce_k
        } else {
          atomicAdd(&out[ro + col], v);      // ws-too-small fallback
        }
      }
    }
  }
}

// ---- kernel 3: out += P (K-split fold, ~50 MB -> ~8 us) --------------------
__global__ __launch_bounds__(256) void reduce_k(float* __restrict__ out,
                                                const float* __restrict__ P) {
  const int n4 = (BATCH * OUT_DIM) / 4;      // 1,048,576 float4s
  for (int i = blockIdx.x * 256 + threadIdx.x; i < n4; i += gridDim.x * 256) {
    float4 o = ((const float4*)out)[i];
    float4 p = ((const float4*)P)[i];
    o.x += p.x; o.y += p.y; o.z += p.z; o.w += p.w;
    ((float4*)out)[i] = o;
  }
}

// ---- host-side launch ------------------------------------------------------
extern "C" void kernel_launch(void* const* d_in, const int* in_sizes, int n_in,
                              void* d_out, int out_size, void* d_ws, size_t ws_size,
                              hipStream_t stream) {
  const float* x      = (const float*)d_in[0];  // (4096, 1024) fp32
  const float* coeffs = (const float*)d_in[1];  // (1024, 8192)
  const float* bw     = (const float*)d_in[2];  // (1024, 1024)
  const float* gsl    = (const float*)d_in[3];  // (1024, 11)
  const float* gstart = (const float*)d_in[4];  // (1024, 1)
  const float* rsp    = (const float*)d_in[5];  // (1,)

  // ws layout: A (75.5 MB f16) | W (18.9 MB f16) | P (16.8 MB f32) = 111.2 MB
  const size_t szA = (size_t)BATCH * KDIM * 2;
  const size_t szW = (size_t)OUT_DIM * KDIM * 2;
  const size_t szP = (size_t)BATCH * OUT_DIM * 4;
  char* ws = (char*)d_ws;
  unsigned short* A  = (unsigned short*)ws;
  unsigned short* W  = (unsigned short*)(ws + szA);
  float*          P  = (float*)(ws + szA + szW);
  float*          out = (float*)d_out;
  const int use_partial = (ws_size >= szA + szW + szP) ? 1 : 0;

  prep_k<<<NBLK_A + NBLK_W, 256, 0, stream>>>(x, coeffs, bw, gsl, gstart, rsp, A, W, out);
  gemm_k<<<NGBLK, 512, 0, stream>>>(A, W, out, P, use_partial);
  if (use_partial) reduce_k<<<2048, 256, 0, stream>>>(out, P);
}